// Round 2
// baseline (806.630 us; speedup 1.0000x reference)
//
#include <hip/hip_runtime.h>
#include <hip/hip_bf16.h>
#include <math.h>

#define HIDDEN 2048
#define SEQ    2048
#define NH     16
#define NKV    2
#define HD     128

typedef __attribute__((ext_vector_type(8))) short s16x8;
typedef __attribute__((ext_vector_type(4))) short s16x4;
typedef __attribute__((ext_vector_type(4))) float f32x4;

__device__ __forceinline__ unsigned short f2bf(float f) {
  union { float f; unsigned int u; } v; v.f = f;
  unsigned int u = v.u;
  u += 0x7FFFu + ((u >> 16) & 1u);
  return (unsigned short)(u >> 16);
}

__device__ __forceinline__ s16x4 cvt4(float4 f) {
  s16x4 r;
  r.x = (short)f2bf(f.x); r.y = (short)f2bf(f.y);
  r.z = (short)f2bf(f.z); r.w = (short)f2bf(f.w);
  return r;
}

__device__ __forceinline__ f32x4 mfma16(s16x8 a, s16x8 b, f32x4 c) {
  return __builtin_amdgcn_mfma_f32_16x16x32_bf16(a, b, c, 0, 0, 0);
}

// ---------------------------------------------------------------------------
// Kernel 1: QKV projection + RoPE (Q,K) / transpose-store (V).
// A (SEQ x HIDDEN, f32) @ W^T (HD x HIDDEN, f32), bf16 MFMA compute.
// Tile: M=128 (grid.x), N=128 (=HD). 4 waves, each 32 rows x 128 cols.
// f32 -> bf16 conversion happens during LDS staging.
// ---------------------------------------------------------------------------
__global__ void __launch_bounds__(256)
qkv_rope_kernel(const float* __restrict__ q_hidden,
                const float* __restrict__ k_hidden,
                const float* __restrict__ v_hidden,
                const float* __restrict__ q_w,
                const float* __restrict__ k_w,
                const float* __restrict__ v_w,
                const int* __restrict__ pos_ids,
                unsigned short* __restrict__ Qb,   // [16][2048][128] bf16
                unsigned short* __restrict__ Kb,   // [2][2048][128]  bf16
                unsigned short* __restrict__ Vtb)  // [2][128][2048]  bf16
{
  const int mt  = blockIdx.x;   // 0..15  (row tile)
  const int bid = blockIdx.y;   // 0..19  (16 Q, 2 K, 2 V)

  const float* A;
  const float* B;
  int mode, head;
  if (bid < 16)      { mode = 0; head = bid;      A = q_hidden + (size_t)head*SEQ*HIDDEN; B = q_w + (size_t)head*HD*HIDDEN; }
  else if (bid < 18) { mode = 1; head = bid - 16; A = k_hidden + (size_t)head*SEQ*HIDDEN; B = k_w + (size_t)head*HD*HIDDEN; }
  else               { mode = 2; head = bid - 18; A = v_hidden + (size_t)head*SEQ*HIDDEN; B = v_w + (size_t)head*HD*HIDDEN; }

  // padded stride 40 elems (80B) keeps ds_read_b128 at 2-way (free) conflicts
  __shared__ __align__(16) unsigned short Asm[128 * 40];
  __shared__ __align__(16) unsigned short Bsm[128 * 40];

  const int tid  = threadIdx.x;
  const int w    = tid >> 6;
  const int lane = tid & 63;
  const int quad = lane >> 4;
  const int col  = lane & 15;
  const int srow = tid >> 3;   // staging row 0..31
  const int schk = tid & 7;    // staging 4-float chunk 0..7

  f32x4 acc[2][8];
  #pragma unroll
  for (int i = 0; i < 2; i++)
    #pragma unroll
    for (int j = 0; j < 8; j++)
      acc[i][j] = (f32x4){0.f, 0.f, 0.f, 0.f};

  const int row0 = mt * 128;

  for (int k0 = 0; k0 < HIDDEN; k0 += 32) {
    #pragma unroll
    for (int p = 0; p < 4; p++) {
      int r = srow + p * 32;
      float4 va = *(const float4*)(A + (size_t)(row0 + r) * HIDDEN + k0 + schk * 4);
      float4 vb = *(const float4*)(B + (size_t)r * HIDDEN + k0 + schk * 4);
      *(s16x4*)&Asm[r * 40 + schk * 4] = cvt4(va);
      *(s16x4*)&Bsm[r * 40 + schk * 4] = cvt4(vb);
    }
    __syncthreads();
    s16x8 af0 = *(const s16x8*)&Asm[(w * 32 + col) * 40 + quad * 8];
    s16x8 af1 = *(const s16x8*)&Asm[(w * 32 + 16 + col) * 40 + quad * 8];
    #pragma unroll
    for (int j = 0; j < 8; j++) {
      s16x8 bf = *(const s16x8*)&Bsm[(j * 16 + col) * 40 + quad * 8];
      acc[0][j] = mfma16(af0, bf, acc[0][j]);
      acc[1][j] = mfma16(af1, bf, acc[1][j]);
    }
    __syncthreads();
  }

  if (mode < 2) {
    // RoPE epilogue. acc (i,j,reg r): row l = row0 + w*32 + i*16 + quad*4 + r,
    // col h = j*16 + col. Pair h <-> h+64 is acc[i][j+4][r].
    unsigned short* Cb = (mode == 0) ? (Qb + (size_t)head * SEQ * HD)
                                     : (Kb + (size_t)head * SEQ * HD);
    const float scl = (mode == 0) ? 0.08838834764831845f : 1.0f; // 1/sqrt(128) folded into Q
    float invf[4];
    #pragma unroll
    for (int j = 0; j < 4; j++)
      invf[j] = __powf(1000000.0f, -(float)(j * 16 + col) * (1.0f / 64.0f));
    #pragma unroll
    for (int i = 0; i < 2; i++) {
      #pragma unroll
      for (int r = 0; r < 4; r++) {
        int l = row0 + w * 32 + i * 16 + quad * 4 + r;
        float p = (float)pos_ids[l];
        unsigned short* crow = Cb + (size_t)l * HD;
        #pragma unroll
        for (int j = 0; j < 4; j++) {
          float ss, cc;
          sincosf(p * invf[j], &ss, &cc);
          float x1 = acc[i][j][r];       // h < 64
          float x2 = acc[i][j + 4][r];   // h + 64
          crow[j * 16 + col]       = f2bf((x1 * cc - x2 * ss) * scl);
          crow[(j + 4) * 16 + col] = f2bf((x2 * cc + x1 * ss) * scl);
        }
      }
    }
  } else {
    // V: store transposed Vt[h][s]
    unsigned short* Cb = Vtb + (size_t)head * HD * SEQ;
    #pragma unroll
    for (int i = 0; i < 2; i++)
      #pragma unroll
      for (int r = 0; r < 4; r++) {
        int l = row0 + w * 32 + i * 16 + quad * 4 + r;
        #pragma unroll
        for (int j = 0; j < 8; j++) {
          int h = j * 16 + col;
          Cb[(size_t)h * SEQ + l] = f2bf(acc[i][j][r]);
        }
      }
  }
}

// ---------------------------------------------------------------------------
// Kernel 2: flash attention (causal, GQA). One block per (q-tile of 128, head).
// All-bf16 workspace tensors; unchanged from round 1.
// ---------------------------------------------------------------------------
__global__ void __launch_bounds__(256)
attn_kernel(const unsigned short* __restrict__ Qb,
            const unsigned short* __restrict__ Kb,
            const unsigned short* __restrict__ Vtb,
            unsigned short* __restrict__ Ob)   // [16][2048][128] bf16
{
  const int qt = blockIdx.x;   // 0..15
  const int n  = blockIdx.y;   // 0..15
  const int kv = n >> 3;

  const int tid  = threadIdx.x;
  const int w    = tid >> 6;
  const int lane = tid & 63;
  const int quad = lane >> 4;
  const int col  = lane & 15;

  // per-wave P buffer: 32 rows x 128 cols, stride 136
  __shared__ __align__(16) unsigned short Psm[4][32 * 136];
  unsigned short* Pw = &Psm[w][0];

  const unsigned short* Qh = Qb  + (size_t)n  * SEQ * HD;
  const unsigned short* Kh = Kb  + (size_t)kv * SEQ * HD;
  const unsigned short* Vh = Vtb + (size_t)kv * HD * SEQ;

  const int qrow0 = qt * 128 + w * 32;

  // Q fragments (A-operand layout), registers for whole block
  s16x8 qfrag[2][4];
  #pragma unroll
  for (int i = 0; i < 2; i++)
    #pragma unroll
    for (int kk = 0; kk < 4; kk++)
      qfrag[i][kk] = *(const s16x8*)(Qh + (size_t)(qrow0 + i * 16 + col) * HD + kk * 32 + quad * 8);

  f32x4 oacc[2][8];
  #pragma unroll
  for (int i = 0; i < 2; i++)
    #pragma unroll
    for (int j = 0; j < 8; j++)
      oacc[i][j] = (f32x4){0.f, 0.f, 0.f, 0.f};
  float mst[2][4], lst[2][4];
  #pragma unroll
  for (int i = 0; i < 2; i++)
    #pragma unroll
    for (int r = 0; r < 4; r++) { mst[i][r] = -3e38f; lst[i][r] = 0.f; }

  for (int st = 0; st <= qt; st++) {
    // ---- S = Q @ K^T (scale pre-folded into Q) ----
    f32x4 sc[2][8];
    #pragma unroll
    for (int i = 0; i < 2; i++)
      #pragma unroll
      for (int j = 0; j < 8; j++)
        sc[i][j] = (f32x4){0.f, 0.f, 0.f, 0.f};
    #pragma unroll
    for (int kk = 0; kk < 4; kk++) {
      #pragma unroll
      for (int j = 0; j < 8; j++) {
        s16x8 kf = *(const s16x8*)(Kh + (size_t)(st * 128 + j * 16 + col) * HD + kk * 32 + quad * 8);
        sc[0][j] = mfma16(qfrag[0][kk], kf, sc[0][j]);
        sc[1][j] = mfma16(qfrag[1][kk], kf, sc[1][j]);
      }
    }
    // ---- causal mask on diagonal tile ----
    if (st == qt) {
      #pragma unroll
      for (int i = 0; i < 2; i++)
        #pragma unroll
        for (int j = 0; j < 8; j++)
          #pragma unroll
          for (int r = 0; r < 4; r++) {
            int lloc = w * 32 + i * 16 + quad * 4 + r;
            int sloc = j * 16 + col;
            if (sloc > lloc) sc[i][j][r] = -1e30f;
          }
    }
    // ---- online softmax (per-row; 16-lane xor shuffles stay in quad) ----
    #pragma unroll
    for (int i = 0; i < 2; i++) {
      #pragma unroll
      for (int r = 0; r < 4; r++) {
        float mx = sc[i][0][r];
        #pragma unroll
        for (int j = 1; j < 8; j++) mx = fmaxf(mx, sc[i][j][r]);
        #pragma unroll
        for (int off = 1; off < 16; off <<= 1) mx = fmaxf(mx, __shfl_xor(mx, off, 64));
        float mnew = fmaxf(mst[i][r], mx);
        float alpha = __expf(mst[i][r] - mnew);
        float lsum = 0.f;
        #pragma unroll
        for (int j = 0; j < 8; j++) {
          float p = __expf(sc[i][j][r] - mnew);
          sc[i][j][r] = p;
          lsum += p;
        }
        #pragma unroll
        for (int off = 1; off < 16; off <<= 1) lsum += __shfl_xor(lsum, off, 64);
        lst[i][r] = lst[i][r] * alpha + lsum;
        mst[i][r] = mnew;
        #pragma unroll
        for (int j = 0; j < 8; j++) oacc[i][j][r] *= alpha;
      }
    }
    // ---- P: C-layout regs -> LDS (bf16) ----
    #pragma unroll
    for (int i = 0; i < 2; i++)
      #pragma unroll
      for (int j = 0; j < 8; j++)
        #pragma unroll
        for (int r = 0; r < 4; r++)
          Pw[(i * 16 + quad * 4 + r) * 136 + j * 16 + col] = f2bf(sc[i][j][r]);
    __syncthreads();
    // ---- O += P @ V ----
    s16x8 pfrag[2][4];
    #pragma unroll
    for (int i = 0; i < 2; i++)
      #pragma unroll
      for (int kk = 0; kk < 4; kk++)
        pfrag[i][kk] = *(const s16x8*)&Pw[(i * 16 + col) * 136 + kk * 32 + quad * 8];
    #pragma unroll
    for (int j = 0; j < 8; j++) {
      #pragma unroll
      for (int kk = 0; kk < 4; kk++) {
        s16x8 vf = *(const s16x8*)(Vh + (size_t)(j * 16 + col) * SEQ + st * 128 + kk * 32 + quad * 8);
        oacc[0][j] = mfma16(pfrag[0][kk], vf, oacc[0][j]);
        oacc[1][j] = mfma16(pfrag[1][kk], vf, oacc[1][j]);
      }
    }
  }

  // ---- finalize + store attn (bf16) ----
  unsigned short* Oh = Ob + ((size_t)n * SEQ + qrow0) * HD;
  #pragma unroll
  for (int i = 0; i < 2; i++) {
    #pragma unroll
    for (int r = 0; r < 4; r++) {
      float inv = 1.0f / lst[i][r];
      #pragma unroll
      for (int j = 0; j < 8; j++)
        Oh[(i * 16 + quad * 4 + r) * HD + j * 16 + col] = f2bf(oacc[i][j][r] * inv);
    }
  }
}

// ---------------------------------------------------------------------------
// Kernel 3: output projection. Per head: attn (2048x128 bf16) @ ow_head^T
// (128x2048 from f32 o_w). Output f32.
// ---------------------------------------------------------------------------
__global__ void __launch_bounds__(256)
oproj_kernel(const unsigned short* __restrict__ Attn,  // [16][2048][128] bf16
             const float* __restrict__ Ow,             // [2048][2048] f32
             float* __restrict__ Out)                  // [16][2048][2048] f32
{
  const int mt = blockIdx.x;  // row tile 0..15
  const int nt = blockIdx.y;  // col tile 0..15
  const int n  = blockIdx.z;  // head 0..15

  __shared__ __align__(16) unsigned short Asm[128 * 40];
  __shared__ __align__(16) unsigned short Bsm[128 * 40];

  const int tid  = threadIdx.x;
  const int w    = tid >> 6;
  const int lane = tid & 63;
  const int quad = lane >> 4;
  const int col  = lane & 15;
  const int srowA = tid >> 2;  // 0..63 (bf16 A staging: 16B chunks)
  const int schkA = tid & 3;
  const int srowB = tid >> 3;  // 0..31 (f32 B staging: 4-float chunks)
  const int schkB = tid & 7;

  const unsigned short* A = Attn + (size_t)n * SEQ * HD + (size_t)mt * 128 * HD;
  const float* B = Ow + (size_t)nt * 128 * HIDDEN + n * HD;  // B^T row d: Ow[d][n*128+h]

  f32x4 acc[2][8];
  #pragma unroll
  for (int i = 0; i < 2; i++)
    #pragma unroll
    for (int j = 0; j < 8; j++)
      acc[i][j] = (f32x4){0.f, 0.f, 0.f, 0.f};

  for (int k0 = 0; k0 < HD; k0 += 32) {
    #pragma unroll
    for (int p = 0; p < 2; p++) {
      int r = srowA + p * 64;
      s16x8 va = *(const s16x8*)(A + (size_t)r * HD + k0 + schkA * 8);
      *(s16x8*)&Asm[r * 40 + schkA * 8] = va;
    }
    #pragma unroll
    for (int p = 0; p < 4; p++) {
      int r = srowB + p * 32;
      float4 vb = *(const float4*)(B + (size_t)r * HIDDEN + k0 + schkB * 4);
      *(s16x4*)&Bsm[r * 40 + schkB * 4] = cvt4(vb);
    }
    __syncthreads();
    s16x8 af0 = *(const s16x8*)&Asm[(w * 32 + col) * 40 + quad * 8];
    s16x8 af1 = *(const s16x8*)&Asm[(w * 32 + 16 + col) * 40 + quad * 8];
    #pragma unroll
    for (int j = 0; j < 8; j++) {
      s16x8 bf = *(const s16x8*)&Bsm[(j * 16 + col) * 40 + quad * 8];
      acc[0][j] = mfma16(af0, bf, acc[0][j]);
      acc[1][j] = mfma16(af1, bf, acc[1][j]);
    }
    __syncthreads();
  }

  float* C = Out + (size_t)n * SEQ * HIDDEN + (size_t)(mt * 128) * HIDDEN + nt * 128;
  #pragma unroll
  for (int i = 0; i < 2; i++)
    #pragma unroll
    for (int r = 0; r < 4; r++) {
      int lr = w * 32 + i * 16 + quad * 4 + r;
      #pragma unroll
      for (int j = 0; j < 8; j++)
        C[(size_t)lr * HIDDEN + j * 16 + col] = acc[i][j][r];
    }
}

// ---------------------------------------------------------------------------
extern "C" void kernel_launch(void* const* d_in, const int* in_sizes, int n_in,
                              void* d_out, int out_size, void* d_ws, size_t ws_size,
                              hipStream_t stream) {
  (void)in_sizes; (void)n_in; (void)out_size; (void)ws_size;
  const float* q_hidden = (const float*)d_in[0];
  const float* k_hidden = (const float*)d_in[1];
  const float* v_hidden = (const float*)d_in[2];
  /* d_in[3] attention_mask: causal, applied analytically */
  const int*   pos      = (const int*)d_in[4];
  const float* q_w      = (const float*)d_in[5];
  const float* k_w      = (const float*)d_in[6];
  const float* v_w      = (const float*)d_in[7];
  const float* o_w      = (const float*)d_in[8];
  float* out = (float*)d_out;

  unsigned short* Qb  = (unsigned short*)d_ws;                 // 16*2048*128 bf16
  unsigned short* Kb  = Qb  + (size_t)NH  * SEQ * HD;          // 2*2048*128
  unsigned short* Vtb = Kb  + (size_t)NKV * SEQ * HD;          // 2*128*2048
  unsigned short* Ab  = Vtb + (size_t)NKV * HD * SEQ;          // 16*2048*128

  qkv_rope_kernel<<<dim3(16, 20), 256, 0, stream>>>(q_hidden, k_hidden, v_hidden,
                                                    q_w, k_w, v_w, pos, Qb, Kb, Vtb);
  attn_kernel<<<dim3(16, 16), 256, 0, stream>>>(Qb, Kb, Vtb, Ab);
  oproj_kernel<<<dim3(16, 16, 16), 256, 0, stream>>>(Ab, o_w, out);
}